// Round 1
// baseline (103.600 us; speedup 1.0000x reference)
//
#include <hip/hip_runtime.h>
#include <math.h>

#define BB 16
#define SS 2048
#define EE 8
#define HH 2
#define DK 4
#define ROWS 64       // query rows per block
#define JCHUNK (SS / 2)
#define THREADS 256

__device__ __forceinline__ float fast_exp2(float x) {
#if defined(__has_builtin)
#if __has_builtin(__builtin_amdgcn_exp2f)
  return __builtin_amdgcn_exp2f(x);
#else
  return exp2f(x);
#endif
#else
  return exp2f(x);
#endif
}

__global__ __launch_bounds__(THREADS, 2)
void qattn_kernel(const float* __restrict__ x,
                  const float* __restrict__ theta,
                  const float* __restrict__ w_out,
                  const float* __restrict__ b_out,
                  float* __restrict__ out) {
  // kv[h*SS + s] = cos(x[b,s,h*4 .. h*4+3] + theta[h*4 ..])  (= q = k = v)
  __shared__ float4 kv[HH * SS];  // 64 KB

  const int b = blockIdx.x >> 5;        // 32 tiles per batch element
  const int tile = blockIdx.x & 31;
  const int t = threadIdx.x;

  const float4 th0 = ((const float4*)theta)[0];
  const float4 th1 = ((const float4*)theta)[1];

  // --- stage K = cos(x + theta) for all S rows, both heads (coalesced) ---
  const float4* x4 = (const float4*)x + (size_t)b * (SS * 2);
  for (int idx = t; idx < SS * 2; idx += THREADS) {
    const int s = idx >> 1;
    const int hf = idx & 1;             // which half-row == which head
    float4 xr = x4[idx];
    float4 th = hf ? th1 : th0;
    float4 kvv;
    kvv.x = cosf(xr.x + th.x);
    kvv.y = cosf(xr.y + th.y);
    kvv.z = cosf(xr.z + th.z);
    kvv.w = cosf(xr.w + th.w);
    kv[hf * SS + s] = kvv;
  }
  __syncthreads();

  // --- thread mapping: wave-uniform (head, key-chunk); lane = query row ---
  const int r  = t & 63;                // row within tile (lane id)
  const int h  = (t >> 6) & 1;          // head (uniform per wave)
  const int jc = t >> 7;                // key chunk 0/1 (uniform per wave)
  const int row = tile * ROWS + r;

  // fold 1/sqrt(dk)=0.5 and log2(e) into q so inner loop uses exp2 directly
  const float K_SCALE = 0.72134752044448170367f;  // 0.5 * log2(e)
  float4 q = kv[h * SS + row];
  q.x *= K_SCALE; q.y *= K_SCALE; q.z *= K_SCALE; q.w *= K_SCALE;

  // scores are bounded in [-2,2] -> exp never overflows -> no running max,
  // so partial (acc, l) over key chunks combine by plain addition.
  float l = 0.f;
  float ax = 0.f, ay = 0.f, az = 0.f, aw = 0.f;
  const float4* kp = &kv[h * SS + jc * JCHUNK];
#pragma unroll 8
  for (int j = 0; j < JCHUNK; ++j) {
    float4 k4 = kp[j];                  // wave-uniform address: LDS broadcast
    float sc = fmaf(q.x, k4.x, fmaf(q.y, k4.y, fmaf(q.z, k4.z, q.w * k4.w)));
    float p = fast_exp2(sc);
    l += p;
    ax = fmaf(p, k4.x, ax);
    ay = fmaf(p, k4.y, ay);
    az = fmaf(p, k4.z, az);
    aw = fmaf(p, k4.w, aw);
  }

  __syncthreads();  // everyone done reading kv; reuse its LDS space
  float* part = (float*)kv;             // [jc][h][r][5]  (1280 floats)
  float* ex   = (float*)kv + 4096;      // [ROWS][8]      (512 floats)
  {
    float* p5 = part + (((jc * 2 + h) * ROWS + r) * 5);
    p5[0] = ax; p5[1] = ay; p5[2] = az; p5[3] = aw; p5[4] = l;
  }
  __syncthreads();

  if (t < 128) {
    const int rr = t & 63;
    const int hh = t >> 6;
    const float* a0 = part + (((0 * 2 + hh) * ROWS + rr) * 5);
    const float* a1 = part + (((1 * 2 + hh) * ROWS + rr) * 5);
    const float inv = 1.0f / (a0[4] + a1[4]);
    ex[rr * 8 + hh * 4 + 0] = (a0[0] + a1[0]) * inv;
    ex[rr * 8 + hh * 4 + 1] = (a0[1] + a1[1]) * inv;
    ex[rr * 8 + hh * 4 + 2] = (a0[2] + a1[2]) * inv;
    ex[rr * 8 + hh * 4 + 3] = (a0[3] + a1[3]) * inv;
  }
  __syncthreads();

  // --- fused out-projection: out[b,s,:] = o @ w_out^T + b_out ---
  if (t < 128) {
    const int rr = t >> 1;              // row within tile
    const int hf = t & 1;               // which 4 output columns
    const int e0 = hf * 4;
    float o[8];
#pragma unroll
    for (int j2 = 0; j2 < 8; ++j2) o[j2] = ex[rr * 8 + j2];
    float c0 = b_out[e0 + 0];
    float c1 = b_out[e0 + 1];
    float c2 = b_out[e0 + 2];
    float c3 = b_out[e0 + 3];
#pragma unroll
    for (int j2 = 0; j2 < 8; ++j2) {
      const float ov = o[j2];
      c0 = fmaf(ov, w_out[(e0 + 0) * 8 + j2], c0);
      c1 = fmaf(ov, w_out[(e0 + 1) * 8 + j2], c1);
      c2 = fmaf(ov, w_out[(e0 + 2) * 8 + j2], c2);
      c3 = fmaf(ov, w_out[(e0 + 3) * 8 + j2], c3);
    }
    const int grow = b * SS + tile * ROWS + rr;
    ((float4*)out)[grow * 2 + hf] = make_float4(c0, c1, c2, c3);
  }
}

extern "C" void kernel_launch(void* const* d_in, const int* in_sizes, int n_in,
                              void* d_out, int out_size, void* d_ws, size_t ws_size,
                              hipStream_t stream) {
  const float* x     = (const float*)d_in[0];
  const float* theta = (const float*)d_in[1];
  const float* w_out = (const float*)d_in[2];
  const float* b_out = (const float*)d_in[3];
  float* out = (float*)d_out;
  (void)in_sizes; (void)n_in; (void)out_size; (void)d_ws; (void)ws_size;

  dim3 grid(BB * (SS / ROWS));  // 16 * 32 = 512 blocks, 64KB LDS -> 2 blocks/CU
  qattn_kernel<<<grid, THREADS, 0, stream>>>(x, theta, w_out, b_out, out);
}

// Round 2
// 99.029 us; speedup vs baseline: 1.0462x; 1.0462x over previous
//
#include <hip/hip_runtime.h>
#include <math.h>

#define BB 16
#define SS 2048
#define EE 8
#define HH 2
#define ROWS 128        // query rows per block (tile)
#define TILES (SS / ROWS)
#define NCHUNK 4
#define CHUNK (SS / NCHUNK)   // 512 keys per wave
#define THREADS 512

typedef float vf2 __attribute__((ext_vector_type(2)));

#if defined(__has_builtin)
#if __has_builtin(__builtin_elementwise_fma)
#define HAS_EW_FMA 1
#endif
#endif

__device__ __forceinline__ float fast_exp2(float x) {
#if defined(__has_builtin)
#if __has_builtin(__builtin_amdgcn_exp2f)
  return __builtin_amdgcn_exp2f(x);
#else
  return exp2f(x);
#endif
#else
  return exp2f(x);
#endif
}

__device__ __forceinline__ vf2 pk_fma(vf2 a, vf2 b, vf2 c) {
#ifdef HAS_EW_FMA
  return __builtin_elementwise_fma(a, b, c);
#else
  vf2 r; r.x = fmaf(a.x, b.x, c.x); r.y = fmaf(a.y, b.y, c.y); return r;
#endif
}

__global__ __launch_bounds__(THREADS, 4)
void qattn_kernel(const float* __restrict__ x,
                  const float* __restrict__ theta,
                  const float* __restrict__ w_out,
                  const float* __restrict__ b_out,
                  float* __restrict__ out) {
  // kv[h*SS + s] = cos(x[b,s,h*4..h*4+3] + theta[h*4..])  (q == k == v)
  __shared__ float4 kv[HH * SS];  // 64 KB

  const int b    = blockIdx.x >> 4;     // 16 row-tiles per batch
  const int tile = blockIdx.x & 15;
  const int t    = threadIdx.x;

  const float4 th0 = ((const float4*)theta)[0];
  const float4 th1 = ((const float4*)theta)[1];

  // --- stage cos(x+theta) for all S rows, both heads (coalesced) ---
  const float4* x4 = (const float4*)x + (size_t)b * (SS * 2);
  for (int idx = t; idx < SS * 2; idx += THREADS) {
    const int s  = idx >> 1;
    const int hf = idx & 1;
    float4 xr = x4[idx];
    float4 th = hf ? th1 : th0;
    float4 kvv;
    kvv.x = cosf(xr.x + th.x);
    kvv.y = cosf(xr.y + th.y);
    kvv.z = cosf(xr.z + th.z);
    kvv.w = cosf(xr.w + th.w);
    kv[hf * SS + s] = kvv;
  }
  __syncthreads();

  // --- wave-uniform (head, key-chunk); each lane owns 2 query rows ---
  const int lane = t & 63;
  const int w    = t >> 6;        // wave id 0..7
  const int h    = w & 1;         // head (uniform per wave)
  const int jc   = w >> 1;        // key chunk 0..3 (uniform per wave)
  const int r0   = tile * ROWS + lane;        // row A
  const int r1   = r0 + 64;                   // row B

  const float K_SCALE = 0.72134752044448170367f;  // 0.5 * log2(e)
  float4 q0 = kv[h * SS + r0];
  float4 q1 = kv[h * SS + r1];
  vf2 q0xy = {q0.x * K_SCALE, q0.y * K_SCALE};
  vf2 q0zw = {q0.z * K_SCALE, q0.w * K_SCALE};
  vf2 q1xy = {q1.x * K_SCALE, q1.y * K_SCALE};
  vf2 q1zw = {q1.z * K_SCALE, q1.w * K_SCALE};

  // scores bounded in [-2,2] -> no running max; chunk partials add linearly
  float l0 = 0.f, l1 = 0.f;
  vf2 a0xy = {0.f, 0.f}, a0zw = {0.f, 0.f};
  vf2 a1xy = {0.f, 0.f}, a1zw = {0.f, 0.f};
  const float4* kp = &kv[h * SS + jc * CHUNK];
#pragma unroll 4
  for (int j = 0; j < CHUNK; ++j) {
    float4 k4 = kp[j];              // wave-uniform address: LDS broadcast
    vf2 kxy = {k4.x, k4.y};
    vf2 kzw = {k4.z, k4.w};
    // row A
    vf2 d0 = pk_fma(q0zw, kzw, q0xy * kxy);
    float p0 = fast_exp2(d0.x + d0.y);
    l0 += p0;
    vf2 pp0 = {p0, p0};
    a0xy = pk_fma(pp0, kxy, a0xy);
    a0zw = pk_fma(pp0, kzw, a0zw);
    // row B
    vf2 d1 = pk_fma(q1zw, kzw, q1xy * kxy);
    float p1 = fast_exp2(d1.x + d1.y);
    l1 += p1;
    vf2 pp1 = {p1, p1};
    a1xy = pk_fma(pp1, kxy, a1xy);
    a1zw = pk_fma(pp1, kzw, a1zw);
  }

  __syncthreads();  // all waves done reading kv; reuse its LDS space
  float* part = (float*)kv;               // [jc][h][ROWS][5]  (5120 floats, 20 KB)
  float* ex   = (float*)kv + 5120;        // [ROWS][8]         (1024 floats, 4 KB)
  {
    float* p5 = part + (((jc * HH + h) * ROWS + lane) * 5);
    p5[0] = a0xy.x; p5[1] = a0xy.y; p5[2] = a0zw.x; p5[3] = a0zw.y; p5[4] = l0;
    p5 += 64 * 5;
    p5[0] = a1xy.x; p5[1] = a1xy.y; p5[2] = a1zw.x; p5[3] = a1zw.y; p5[4] = l1;
  }
  __syncthreads();

  // --- merge 4 chunk partials, normalize -> ex[row][8] ---
  if (t < ROWS * HH) {
    const int rr = t >> 1;
    const int hh = t & 1;
    float s0 = 0.f, s1 = 0.f, s2 = 0.f, s3 = 0.f, sl = 0.f;
#pragma unroll
    for (int jcc = 0; jcc < NCHUNK; ++jcc) {
      const float* p5 = part + (((jcc * HH + hh) * ROWS + rr) * 5);
      s0 += p5[0]; s1 += p5[1]; s2 += p5[2]; s3 += p5[3]; sl += p5[4];
    }
    const float inv = 1.0f / sl;
    ex[rr * 8 + hh * 4 + 0] = s0 * inv;
    ex[rr * 8 + hh * 4 + 1] = s1 * inv;
    ex[rr * 8 + hh * 4 + 2] = s2 * inv;
    ex[rr * 8 + hh * 4 + 3] = s3 * inv;
  }
  __syncthreads();

  // --- fused out-projection: out[b,s,:] = o @ w_out^T + b_out ---
  if (t < ROWS * 2) {
    const int rr = t >> 1;              // row within tile
    const int hf = t & 1;               // which 4 output columns
    const int e0 = hf * 4;
    float o[8];
#pragma unroll
    for (int j2 = 0; j2 < 8; ++j2) o[j2] = ex[rr * 8 + j2];
    float c0 = b_out[e0 + 0];
    float c1 = b_out[e0 + 1];
    float c2 = b_out[e0 + 2];
    float c3 = b_out[e0 + 3];
#pragma unroll
    for (int j2 = 0; j2 < 8; ++j2) {
      const float ov = o[j2];
      c0 = fmaf(ov, w_out[(e0 + 0) * 8 + j2], c0);
      c1 = fmaf(ov, w_out[(e0 + 1) * 8 + j2], c1);
      c2 = fmaf(ov, w_out[(e0 + 2) * 8 + j2], c2);
      c3 = fmaf(ov, w_out[(e0 + 3) * 8 + j2], c3);
    }
    const int grow = b * SS + tile * ROWS + rr;
    ((float4*)out)[grow * 2 + hf] = make_float4(c0, c1, c2, c3);
  }
}

extern "C" void kernel_launch(void* const* d_in, const int* in_sizes, int n_in,
                              void* d_out, int out_size, void* d_ws, size_t ws_size,
                              hipStream_t stream) {
  const float* x     = (const float*)d_in[0];
  const float* theta = (const float*)d_in[1];
  const float* w_out = (const float*)d_in[2];
  const float* b_out = (const float*)d_in[3];
  float* out = (float*)d_out;
  (void)in_sizes; (void)n_in; (void)out_size; (void)d_ws; (void)ws_size;

  dim3 grid(BB * TILES);  // 16 * 16 = 256... see below: 16 batches x 16 tiles = 256? No:
  // BB*TILES = 16*16 = 256 blocks of 512 threads, 64KB LDS -> 2 blocks/CU, 16 waves/CU
  qattn_kernel<<<dim3(BB * TILES), THREADS, 0, stream>>>(x, theta, w_out, b_out, out);
}

// Round 3
// 94.229 us; speedup vs baseline: 1.0995x; 1.0509x over previous
//
#include <hip/hip_runtime.h>
#include <math.h>

#define BB 16
#define SS 2048
#define HH 2
#define ROWS 128              // query rows per block
#define TILES (SS / ROWS)     // 16
#define NCHUNK 16             // key chunks == waves per block
#define CHUNK (SS / NCHUNK)   // 128 keys per wave
#define THREADS 1024

typedef float vf2 __attribute__((ext_vector_type(2)));

#if defined(__has_builtin)
#if __has_builtin(__builtin_elementwise_fma)
#define HAS_EW_FMA 1
#endif
#endif

__device__ __forceinline__ float fast_exp2(float x) {
#if defined(__has_builtin)
#if __has_builtin(__builtin_amdgcn_exp2f)
  return __builtin_amdgcn_exp2f(x);
#else
  return exp2f(x);
#endif
#else
  return exp2f(x);
#endif
}

__device__ __forceinline__ vf2 pk_fma(vf2 a, vf2 b, vf2 c) {
#ifdef HAS_EW_FMA
  return __builtin_elementwise_fma(a, b, c);
#else
  vf2 r; r.x = fmaf(a.x, b.x, c.x); r.y = fmaf(a.y, b.y, c.y); return r;
#endif
}

// grid: 16 batches x 16 row-tiles x 2 heads = 512 blocks -> 2 blocks/CU
// block: 1024 threads = 16 waves; wave w owns key-chunk w; lane owns 2 rows
__global__ __launch_bounds__(THREADS, 8)
void qattn_kernel(const float* __restrict__ x,
                  const float* __restrict__ theta,
                  const float* __restrict__ w_out,
                  const float* __restrict__ b_out,
                  float* __restrict__ out) {
  // phase 1: sm4[0..2047]  = kv for this head (32 KB)
  // phase 2: sm4[0..2047]  = accm[jc][rowInTile] (float4 partials, 32 KB)
  //          lm[0..2047]   = l partials overlay at +32 KB (8 KB)
  __shared__ float4 sm4[SS + SS / 4];   // 40 KB
  float* lm = (float*)(sm4 + SS);

  const int bid  = blockIdx.x;
  const int b    = bid >> 5;            // 32 blocks per batch
  const int tile = (bid >> 1) & 15;
  const int h    = bid & 1;
  const int t    = threadIdx.x;

  // --- stage cos(x + theta) for this head's 4 wires, all S rows ---
  const float4 th = ((const float4*)theta)[h];
  const float4* x4 = (const float4*)x + (size_t)b * (SS * 2) + h;
  for (int s = t; s < SS; s += THREADS) {
    float4 xr = x4[2 * s];
    float4 kvv;
    kvv.x = __cosf(xr.x + th.x);
    kvv.y = __cosf(xr.y + th.y);
    kvv.z = __cosf(xr.z + th.z);
    kvv.w = __cosf(xr.w + th.w);
    sm4[s] = kvv;
  }
  __syncthreads();

  // --- wave-uniform key chunk; each lane owns rows (r0, r0+64) ---
  const int lane = t & 63;
  const int jc   = t >> 6;              // 0..15, uniform per wave
  const int r0   = tile * ROWS + lane;
  const int r1   = r0 + 64;

  const float K_SCALE = 0.72134752044448170367f;  // 0.5 * log2(e)
  float4 q0 = sm4[r0];
  float4 q1 = sm4[r1];
  vf2 q0xy = {q0.x * K_SCALE, q0.y * K_SCALE};
  vf2 q0zw = {q0.z * K_SCALE, q0.w * K_SCALE};
  vf2 q1xy = {q1.x * K_SCALE, q1.y * K_SCALE};
  vf2 q1zw = {q1.z * K_SCALE, q1.w * K_SCALE};

  // scores bounded in [-2,2] -> no running max; chunk partials add linearly
  float l0 = 0.f, l1 = 0.f;
  vf2 a0xy = {0.f, 0.f}, a0zw = {0.f, 0.f};
  vf2 a1xy = {0.f, 0.f}, a1zw = {0.f, 0.f};
  const float4* kp = sm4 + jc * CHUNK;
#pragma unroll 8
  for (int j = 0; j < CHUNK; ++j) {
    float4 k4 = kp[j];                  // wave-uniform address: LDS broadcast
    vf2 kxy = {k4.x, k4.y};
    vf2 kzw = {k4.z, k4.w};
    vf2 d0 = pk_fma(q0zw, kzw, q0xy * kxy);
    float p0 = fast_exp2(d0.x + d0.y);
    vf2 d1 = pk_fma(q1zw, kzw, q1xy * kxy);
    float p1 = fast_exp2(d1.x + d1.y);
    l0 += p0;
    vf2 pp0 = {p0, p0};
    a0xy = pk_fma(pp0, kxy, a0xy);
    a0zw = pk_fma(pp0, kzw, a0zw);
    l1 += p1;
    vf2 pp1 = {p1, p1};
    a1xy = pk_fma(pp1, kxy, a1xy);
    a1zw = pk_fma(pp1, kzw, a1zw);
  }

  __syncthreads();   // all waves done reading kv; reuse LDS for partials
  {
    float4 v0 = make_float4(a0xy.x, a0xy.y, a0zw.x, a0zw.y);
    float4 v1 = make_float4(a1xy.x, a1xy.y, a1zw.x, a1zw.y);
    sm4[jc * ROWS + lane]      = v0;
    sm4[jc * ROWS + lane + 64] = v1;
    lm[jc * ROWS + lane]       = l0;
    lm[jc * ROWS + lane + 64]  = l1;
  }
  __syncthreads();

  // --- merge 16 chunk partials, normalize, project, atomic-accumulate ---
  // 1024 threads = 128 rows x 8 output cols: one atomicAdd per thread
  {
    const int rr = t >> 3;              // row within tile
    const int e  = t & 7;               // output column
    float sx = 0.f, sy = 0.f, sz = 0.f, sw = 0.f, sl = 0.f;
#pragma unroll
    for (int jcc = 0; jcc < NCHUNK; ++jcc) {
      float4 a = sm4[jcc * ROWS + rr];
      sx += a.x; sy += a.y; sz += a.z; sw += a.w;
      sl += lm[jcc * ROWS + rr];
    }
    const float inv = 1.0f / sl;
    const float* wr = w_out + e * 8 + h * 4;
    float val = fmaf(sx * inv, wr[0],
                fmaf(sy * inv, wr[1],
                fmaf(sz * inv, wr[2], (sw * inv) * wr[3])));
    if (h == 0) val += b_out[e];
    atomicAdd(out + ((size_t)(b * SS + tile * ROWS + rr)) * 8 + e, val);
  }
}

extern "C" void kernel_launch(void* const* d_in, const int* in_sizes, int n_in,
                              void* d_out, int out_size, void* d_ws, size_t ws_size,
                              hipStream_t stream) {
  const float* x     = (const float*)d_in[0];
  const float* theta = (const float*)d_in[1];
  const float* w_out = (const float*)d_in[2];
  const float* b_out = (const float*)d_in[3];
  float* out = (float*)d_out;
  (void)in_sizes; (void)n_in; (void)d_ws; (void)ws_size;

  // two head-blocks atomically accumulate into each output cell: zero first
  hipMemsetAsync(d_out, 0, (size_t)out_size * sizeof(float), stream);
  qattn_kernel<<<dim3(BB * TILES * HH), THREADS, 0, stream>>>(x, theta, w_out, b_out, out);
}

// Round 4
// 80.551 us; speedup vs baseline: 1.2862x; 1.1698x over previous
//
#include <hip/hip_runtime.h>
#include <math.h>

#define BB 16
#define SS 2048
#define HH 2
#define ROWS_PER_BLOCK 128
#define ROWS_PER_WAVE 32
#define THREADS1 256
#define NIH 2                  // key-range halves (occupancy split)
#define KEYS_HALF (SS / NIH)   // 1024
#define KT 16                  // keys per inner iteration
#define NITER (KEYS_HALF / KT) // 64
#define KVT_STRIDE 1040        // padded: 1040*2B stride -> +8 banks per row

typedef _Float16 half8 __attribute__((ext_vector_type(8)));
typedef _Float16 half4h __attribute__((ext_vector_type(4)));
typedef float floatx4 __attribute__((ext_vector_type(4)));

__device__ __forceinline__ float fast_exp2(float x) {
  return __builtin_amdgcn_exp2f(x);
}

// k1: per (key-half, b, h, 128-row block): scores via MFMA, exp on VALU,
// PV via MFMA (ones-column gives l). Writes partial (O_num[4], l) to ws.
// ws layout: float ws[NIH][32(bh)][SS][8]  (cols 0-3 = O_num, 4 = l)
__global__ __launch_bounds__(THREADS1, 4)
void qattn_mfma(const float* __restrict__ x,
                const float* __restrict__ theta,
                float* __restrict__ ws) {
  __shared__ half8 s_keys[KEYS_HALF];        // [key][8] f16, hi 4 zeroed (16 KB)
  __shared__ _Float16 s_kvT[5 * KVT_STRIDE]; // rows 0-3 = kv^T, row 4 = ones (10.2 KB)
  __shared__ half4h s_rows[ROWS_PER_BLOCK];  // raw q for this block's rows (1 KB)

  const int bid = blockIdx.x;      // [ih][bh][rb]
  const int rb  = bid & 15;
  const int bh  = (bid >> 4) & 31;
  const int ih  = bid >> 9;
  const int b   = bh >> 1;
  const int h   = bh & 1;
  const int t   = threadIdx.x;

  const float4 th = ((const float4*)theta)[h];
  const float4* xb = (const float4*)x;   // element (b*SS+s)*2 + h

  // --- stage cos(x+theta) as f16: keys (this half), kv^T, own rows ---
  for (int i = t; i < KEYS_HALF; i += THREADS1) {
    const int s = ih * KEYS_HALF + i;
    float4 xr = xb[(size_t)(b * SS + s) * 2 + h];
    _Float16 c0 = (_Float16)__cosf(xr.x + th.x);
    _Float16 c1 = (_Float16)__cosf(xr.y + th.y);
    _Float16 c2 = (_Float16)__cosf(xr.z + th.z);
    _Float16 c3 = (_Float16)__cosf(xr.w + th.w);
    const _Float16 z = (_Float16)0.0f;
    half8 v = {c0, c1, c2, c3, z, z, z, z};
    s_keys[i] = v;
    s_kvT[0 * KVT_STRIDE + i] = c0;
    s_kvT[1 * KVT_STRIDE + i] = c1;
    s_kvT[2 * KVT_STRIDE + i] = c2;
    s_kvT[3 * KVT_STRIDE + i] = c3;
  }
  for (int i = t; i < KVT_STRIDE; i += THREADS1)
    s_kvT[4 * KVT_STRIDE + i] = (_Float16)1.0f;   // ones column -> l
  for (int i = t; i < ROWS_PER_BLOCK; i += THREADS1) {
    const int s = rb * ROWS_PER_BLOCK + i;
    float4 xr = xb[(size_t)(b * SS + s) * 2 + h];
    half4h v = {(_Float16)__cosf(xr.x + th.x), (_Float16)__cosf(xr.y + th.y),
                (_Float16)__cosf(xr.z + th.z), (_Float16)__cosf(xr.w + th.w)};
    s_rows[i] = v;
  }
  __syncthreads();

  const int lane = t & 63;
  const int wv   = t >> 6;        // wave owns 32 rows (two 16-row tiles)
  const int quad = lane >> 4;
  const int l15  = lane & 15;

  // QK B-operand (own rows, scaled by 0.5*log2e), built once.
  // B[k][n]: n = lane&15, k = quad*8+j; only quad0/j<4 nonzero.
  const float KS  = 0.72134752044448170367f;
  const float scl = (lane < 16) ? KS : 0.0f;
  half4h r0 = s_rows[wv * ROWS_PER_WAVE + l15];
  half4h r1 = s_rows[wv * ROWS_PER_WAVE + 16 + l15];
  const _Float16 z = (_Float16)0.0f;
  half8 b0 = {(_Float16)((float)r0[0] * scl), (_Float16)((float)r0[1] * scl),
              (_Float16)((float)r0[2] * scl), (_Float16)((float)r0[3] * scl), z, z, z, z};
  half8 b1 = {(_Float16)((float)r1[0] * scl), (_Float16)((float)r1[1] * scl),
              (_Float16)((float)r1[2] * scl), (_Float16)((float)r1[3] * scl), z, z, z, z};

  // PV B-operand base: B[k=8q+j][n=l15] = kvT[min(n,4)][kb + 4q + j], j<4
  const _Float16* bpv_base =
      s_kvT + (l15 < 4 ? l15 : 4) * KVT_STRIDE + quad * 4;

  floatx4 o0 = {0.f, 0.f, 0.f, 0.f};
  floatx4 o1 = {0.f, 0.f, 0.f, 0.f};
  const floatx4 zf = {0.f, 0.f, 0.f, 0.f};
  half8 apv0 = {z, z, z, z, z, z, z, z};
  half8 apv1 = {z, z, z, z, z, z, z, z};

#pragma unroll 2
  for (int it = 0; it < NITER; ++it) {
    // A (keys): A[m=l15][k=8q+j]; j<4 real (k=d), rest killed by B zeros.
    half8 a = s_keys[it * KT + l15];
    half4h bl = *(const half4h*)(bpv_base + it * KT);
    half8 bpv = {bl[0], bl[1], bl[2], bl[3], z, z, z, z};

    // scores C[key 4q+reg][row l15] * 0.5*log2e
    floatx4 c0 = __builtin_amdgcn_mfma_f32_16x16x32_f16(a, b0, zf, 0, 0, 0);
    floatx4 c1 = __builtin_amdgcn_mfma_f32_16x16x32_f16(a, b1, zf, 0, 0, 0);

    // exp2 -> P tile, directly in PV A-operand layout (m=l15, k slot 8q+j)
    apv0[0] = (_Float16)fast_exp2(c0[0]);
    apv0[1] = (_Float16)fast_exp2(c0[1]);
    apv0[2] = (_Float16)fast_exp2(c0[2]);
    apv0[3] = (_Float16)fast_exp2(c0[3]);
    apv1[0] = (_Float16)fast_exp2(c1[0]);
    apv1[1] = (_Float16)fast_exp2(c1[1]);
    apv1[2] = (_Float16)fast_exp2(c1[2]);
    apv1[3] = (_Float16)fast_exp2(c1[3]);

    o0 = __builtin_amdgcn_mfma_f32_16x16x32_f16(apv0, bpv, o0, 0, 0, 0);
    o1 = __builtin_amdgcn_mfma_f32_16x16x32_f16(apv1, bpv, o1, 0, 0, 0);
  }

  // O/D layout: col n = l15 (kv col; 4 = l), row = quad*4 + reg
  if (l15 < 5) {
    const size_t base =
        ((size_t)(ih * 32 + bh) * SS + rb * ROWS_PER_BLOCK + wv * ROWS_PER_WAVE) * 8;
    float* w0 = ws + base + (size_t)(quad * 4) * 8 + l15;
    float* w1 = ws + base + (size_t)(16 + quad * 4) * 8 + l15;
    w0[0]  = o0[0]; w0[8]  = o0[1]; w0[16] = o0[2]; w0[24] = o0[3];
    w1[0]  = o1[0]; w1[8]  = o1[1]; w1[16] = o1[2]; w1[24] = o1[3];
  }
}

// k2: merge halves, normalize, project 8x8, add bias.
__global__ __launch_bounds__(256)
void qattn_proj(const float* __restrict__ ws,
                const float* __restrict__ w_out,
                const float* __restrict__ b_out,
                float* __restrict__ out) {
  const int gid = blockIdx.x * 256 + threadIdx.x;  // (b, s): 32768 rows
  const int b = gid >> 11;
  const int s = gid & 2047;
  float o[8];
#pragma unroll
  for (int h = 0; h < HH; ++h) {
    const int bh = b * 2 + h;
    const size_t i0 = ((size_t)(0 * 32 + bh) * SS + s) * 8;
    const size_t i1 = ((size_t)(1 * 32 + bh) * SS + s) * 8;
    float4 A  = *(const float4*)(ws + i0);
    float  la = ws[i0 + 4];
    float4 Bv = *(const float4*)(ws + i1);
    float  lb = ws[i1 + 4];
    const float inv = 1.0f / (la + lb);
    o[h * 4 + 0] = (A.x + Bv.x) * inv;
    o[h * 4 + 1] = (A.y + Bv.y) * inv;
    o[h * 4 + 2] = (A.z + Bv.z) * inv;
    o[h * 4 + 3] = (A.w + Bv.w) * inv;
  }
  float r[8];
#pragma unroll
  for (int e = 0; e < 8; ++e) {
    float acc = b_out[e];
#pragma unroll
    for (int j = 0; j < 8; ++j) acc = fmaf(o[j], w_out[e * 8 + j], acc);
    r[e] = acc;
  }
  float* op = out + (size_t)gid * 8;
  *(float4*)op = make_float4(r[0], r[1], r[2], r[3]);
  *(float4*)(op + 4) = make_float4(r[4], r[5], r[6], r[7]);
}

extern "C" void kernel_launch(void* const* d_in, const int* in_sizes, int n_in,
                              void* d_out, int out_size, void* d_ws, size_t ws_size,
                              hipStream_t stream) {
  const float* x     = (const float*)d_in[0];
  const float* theta = (const float*)d_in[1];
  const float* w_out = (const float*)d_in[2];
  const float* b_out = (const float*)d_in[3];
  float* out = (float*)d_out;
  (void)in_sizes; (void)n_in; (void)out_size; (void)ws_size;

  // ws usage: 2*32*2048*8 floats = 4 MB
  qattn_mfma<<<dim3(NIH * 32 * 16), THREADS1, 0, stream>>>(x, theta, (float*)d_ws);
  qattn_proj<<<dim3((BB * SS) / 256), 256, 0, stream>>>((const float*)d_ws, w_out, b_out, out);
}

// Round 6
// 80.148 us; speedup vs baseline: 1.2926x; 1.0050x over previous
//
#include <hip/hip_runtime.h>
#include <math.h>

#define BB 16
#define SS 2048
#define HH 2
#define ROWS_PER_BLOCK 128
#define THREADS1 512          // 8 waves; wave owns one 16-row tile
#define KT 16                 // keys per inner iteration
#define NITER (SS / KT)       // 128
#define KVT_STRIDE 2064       // 4128B row stride == +8 banks (conflict-free, R4-verified)

typedef _Float16 half8 __attribute__((ext_vector_type(8)));
typedef _Float16 half4h __attribute__((ext_vector_type(4)));
typedef _Float16 half2h __attribute__((ext_vector_type(2)));
typedef float floatx4 __attribute__((ext_vector_type(4)));

__device__ __forceinline__ float fast_exp2(float x) {
  return __builtin_amdgcn_exp2f(x);
}

__device__ __forceinline__ half2h pkrtz(float a, float b) {
#if defined(__has_builtin)
#if __has_builtin(__builtin_amdgcn_cvt_pkrtz)
  return __builtin_bit_cast(half2h, __builtin_amdgcn_cvt_pkrtz(a, b));
#else
  half2h r; r[0] = (_Float16)a; r[1] = (_Float16)b; return r;
#endif
#else
  half2h r; r[0] = (_Float16)a; r[1] = (_Float16)b; return r;
#endif
}

// One fused kernel. grid: [b(16)][h(2)][rb(16)] = 512 blocks -> 2 blocks/CU.
// Block: stage kv = cos(x+theta) (f16) for all 2048 keys of its head; 8 waves,
// wave wv sweeps rows [rb*128+wv*16, +16) x all keys: QK via MFMA, exp on
// VALU, PV via MFMA with a ones-column giving the softmax denominator.
// Epilogue: normalize + 8x8 out-projection in-block, atomicAdd per head.
__global__ __launch_bounds__(THREADS1, 4)
void qattn_fused(const float* __restrict__ x,
                 const float* __restrict__ theta,
                 const float* __restrict__ w_out,
                 const float* __restrict__ b_out,
                 float* __restrict__ out) {
  __shared__ half8 s_keys[SS];               // [key][8] f16, hi 4 zeroed (32 KB)
  __shared__ _Float16 s_kvT[5 * KVT_STRIDE]; // rows 0-3 = kv^T, row 4 = ones (20.2 KB)
  __shared__ float po[ROWS_PER_BLOCK * 6];   // epilogue: per-row o[4],l (3 KB)

  const int bid = blockIdx.x;
  const int rb  = bid & 15;
  const int h   = (bid >> 4) & 1;
  const int b   = bid >> 5;
  const int t   = threadIdx.x;

  const float4 th = ((const float4*)theta)[h];
  const float4* xb = (const float4*)x;       // element (b*SS+s)*2 + h

  // --- stage cos(x+theta) as f16: A-rows (keys) and kv^T + ones ---
  for (int s = t; s < SS; s += THREADS1) {
    float4 xr = xb[(size_t)(b * SS + s) * 2 + h];
    _Float16 c0 = (_Float16)__cosf(xr.x + th.x);
    _Float16 c1 = (_Float16)__cosf(xr.y + th.y);
    _Float16 c2 = (_Float16)__cosf(xr.z + th.z);
    _Float16 c3 = (_Float16)__cosf(xr.w + th.w);
    const _Float16 z = (_Float16)0.0f;
    half8 v = {c0, c1, c2, c3, z, z, z, z};
    s_keys[s] = v;
    s_kvT[0 * KVT_STRIDE + s] = c0;
    s_kvT[1 * KVT_STRIDE + s] = c1;
    s_kvT[2 * KVT_STRIDE + s] = c2;
    s_kvT[3 * KVT_STRIDE + s] = c3;
  }
  for (int i = t; i < KVT_STRIDE; i += THREADS1)
    s_kvT[4 * KVT_STRIDE + i] = (_Float16)1.0f;   // ones column -> denominator
  __syncthreads();

  const int lane = t & 63;
  const int wv   = t >> 6;        // wave id 0..7 -> 16-row tile
  const int quad = lane >> 4;
  const int l15  = lane & 15;

  // QK B-operand (this wave's 16 query rows, scaled by 0.5*log2e), built once.
  // B[k=j][n=l15] nonzero only for quad==0, j<4.
  const float KS  = 0.72134752044448170367f;   // 0.5 * log2(e)
  const float scl = (lane < 16) ? KS : 0.0f;
  const int   qrow = rb * ROWS_PER_BLOCK + wv * 16 + l15;
  half4h rq = *(const half4h*)&s_keys[qrow];
  const _Float16 z = (_Float16)0.0f;
  half8 bq = {(_Float16)((float)rq[0] * scl), (_Float16)((float)rq[1] * scl),
              (_Float16)((float)rq[2] * scl), (_Float16)((float)rq[3] * scl),
              z, z, z, z};

  // PV B-operand: B[k=8q+j][n=l15] = kvT[min(l15,4)][kt*16 + 4q + j], j<4
  const _Float16* bbase = s_kvT + (l15 < 4 ? l15 : 4) * KVT_STRIDE + quad * 4;

  floatx4 o = {0.f, 0.f, 0.f, 0.f};
  const floatx4 zf = {0.f, 0.f, 0.f, 0.f};
  half8 apv = {z, z, z, z, z, z, z, z};

#pragma unroll 4
  for (int kt = 0; kt < NITER; ++kt) {
    // QK A-operand: A[m=l15][k=8q+j] = key (kt*16+l15), j<4 real
    half8 a = s_keys[kt * KT + l15];
    half4h bl = *(const half4h*)(bbase + kt * KT);
    half8 bpv = {bl[0], bl[1], bl[2], bl[3], z, z, z, z};

    // scores C[key=4q+reg][row=l15], pre-scaled for exp2
    floatx4 c = __builtin_amdgcn_mfma_f32_16x16x32_f16(a, bq, zf, 0, 0, 0);

    // P tile directly in PV A-operand layout: A[m=l15][k=8q+j] = P[row][key 4q+j]
    half2h p01 = pkrtz(fast_exp2(c[0]), fast_exp2(c[1]));
    half2h p23 = pkrtz(fast_exp2(c[2]), fast_exp2(c[3]));
    apv[0] = p01[0]; apv[1] = p01[1]; apv[2] = p23[0]; apv[3] = p23[1];

    o = __builtin_amdgcn_mfma_f32_16x16x32_f16(apv, bpv, o, 0, 0, 0);
  }

  // O/D layout: col n=l15 (0-3 = numerator wires, 4 = l), row m = quad*4+reg
  if (l15 < 5) {
#pragma unroll
    for (int r = 0; r < 4; ++r)
      po[(wv * 16 + quad * 4 + r) * 6 + l15] = o[r];
  }
  __syncthreads();

  // --- normalize + out-projection; atomicAdd merges the two heads ---
  {
    const int row = t >> 2;           // 0..127
    const int ep  = (t & 3) * 2;      // output cols {ep, ep+1}
    const float* pr = po + row * 6;
    const float inv = 1.0f / pr[4];
    const float o0 = pr[0] * inv, o1 = pr[1] * inv,
                o2 = pr[2] * inv, o3 = pr[3] * inv;
    float* op = out + ((size_t)(b * SS + rb * ROWS_PER_BLOCK + row)) * 8;
#pragma unroll
    for (int k = 0; k < 2; ++k) {
      const int e = ep + k;
      const float* wr = w_out + e * 8 + h * 4;
      float val = fmaf(o0, wr[0], fmaf(o1, wr[1], fmaf(o2, wr[2], o3 * wr[3])));
      if (h == 0) val += b_out[e];
      atomicAdd(op + e, val);
    }
  }
}

extern "C" void kernel_launch(void* const* d_in, const int* in_sizes, int n_in,
                              void* d_out, int out_size, void* d_ws, size_t ws_size,
                              hipStream_t stream) {
  const float* x     = (const float*)d_in[0];
  const float* theta = (const float*)d_in[1];
  const float* w_out = (const float*)d_in[2];
  const float* b_out = (const float*)d_in[3];
  float* out = (float*)d_out;
  (void)in_sizes; (void)n_in; (void)d_ws; (void)ws_size;

  // two head-blocks accumulate into each output cell: zero first
  (void)hipMemsetAsync(d_out, 0, (size_t)out_size * sizeof(float), stream);
  qattn_fused<<<dim3(BB * HH * 16), THREADS1, 0, stream>>>(x, theta, w_out, b_out, out);
}